// Round 13
// baseline (25.895 us; speedup 1.0000x reference)
//
#include <hip/hip_runtime.h>

// BilateralFilter fp32 I/O, 8 images 512x512, 3x3, sigma=0.8.
// v13 = v11 (2x4 tile, packed-fp16, poly-exp) with:
//  - explicit raw/convert split: all 30 A+B loads issued before any cvt
//    (kills per-plane load->cvt->load vmcnt serialization);
//  - side-row loads prefetched under ~700 cyc of main-pass compute;
//  - center taps folded (wd=1, wc=3 exactly);
//  - exact zero-pad semantics at image top/bottom (zeroed window, no skip).

typedef _Float16 h2 __attribute__((ext_vector_type(2)));

constexpr int HH = 512, WW = 512, HW = HH * WW;

__device__ __forceinline__ h2 H2c(float v) { return h2{(_Float16)v, (_Float16)v}; }
__device__ __forceinline__ h2 pkrtz(float a, float b) {
    return __builtin_bit_cast(h2, __builtin_amdgcn_cvt_pkrtz(a, b));
}

// w(s)=e^(-0.78125*s), s=d^2 in [0,1]; deg-4 Taylor at s=0.5 (rel err ~5e-5)
__device__ __forceinline__ h2 wpoly(h2 d) {
    h2 v = d * d + H2c(-0.5f);
    h2 w = H2c(-0.0537742f) + v * H2c(0.0105029f);
    w = H2c(0.206495f) + v * w;
    w = H2c(-0.528620f) + v * w;
    w = H2c(0.676634f) + v * w;
    return w;
}

#define WS0f 0.2724967f
#define WS1f 0.1247577f
#define WS2f 0.0571180f

struct RW  { h2 d[5], m[5], x[5], y[5], z[5]; };            // 25 VGPR
struct Raw { float4 dm, mm, xm, ym, zm;                     // 40 VGPR
             float2 dl, dr, ml, mr, xl, xr, yl, yr, zl, zr; };
struct Acc { h2 swd, swc, st, s0, s1, s2; };

__global__ __launch_bounds__(256) void bilateral_v13(
    const float* __restrict__ depth,
    const float* __restrict__ color,
    const float* __restrict__ mask,
    float* __restrict__ out)
{
    const int lane = threadIdx.x & 63;
    const int wg   = blockIdx.x * 4 + (threadIdx.x >> 6);
    const int n    = wg >> 9;
    const int rem  = wg & 511;
    const int hp   = rem >> 1;              // row-pair 0..255
    const int half = rem & 1;
    const int rA   = hp * 2;
    const int c0   = half * 256 + lane * 4;

    const float* dptr = depth + (size_t)n * HW;
    const float* mptr = mask  + (size_t)n * HW;
    const float* xptr = color + (size_t)n * 3 * HW;
    const float* yptr = xptr + HW;
    const float* zptr = xptr + 2 * HW;

    const bool hasL = (c0 > 0);
    const bool hasR = (c0 < WW - 4);
    const int  colL = hasL ? c0 - 2 : c0;   // aligned float2, clamped
    const int  colR = hasR ? c0 + 4 : c0;

// Issue all 15 loads of one row (5 planes x [x4 main, x2 left, x2 right]).
#define LOADRAW(R_, r) do {                                                  \
    const int _o = (r) * WW;                                                 \
    R_.dm = *reinterpret_cast<const float4*>(dptr + _o + c0);                \
    R_.mm = *reinterpret_cast<const float4*>(mptr + _o + c0);                \
    R_.xm = *reinterpret_cast<const float4*>(xptr + _o + c0);                \
    R_.ym = *reinterpret_cast<const float4*>(yptr + _o + c0);                \
    R_.zm = *reinterpret_cast<const float4*>(zptr + _o + c0);                \
    R_.dl = *reinterpret_cast<const float2*>(dptr + _o + colL);              \
    R_.ml = *reinterpret_cast<const float2*>(mptr + _o + colL);              \
    R_.xl = *reinterpret_cast<const float2*>(xptr + _o + colL);              \
    R_.yl = *reinterpret_cast<const float2*>(yptr + _o + colL);              \
    R_.zl = *reinterpret_cast<const float2*>(zptr + _o + colL);              \
    R_.dr = *reinterpret_cast<const float2*>(dptr + _o + colR);              \
    R_.mr = *reinterpret_cast<const float2*>(mptr + _o + colR);              \
    R_.xr = *reinterpret_cast<const float2*>(xptr + _o + colR);              \
    R_.yr = *reinterpret_cast<const float2*>(yptr + _o + colR);              \
    R_.zr = *reinterpret_cast<const float2*>(zptr + _o + colR);              \
} while (0)

#define CVT1(dst, Qm, Ql, Qr) do {                                           \
    dst[0] = pkrtz(hasL ? (Ql).y : 0.0f, (Qm).x);                            \
    dst[1] = pkrtz((Qm).x, (Qm).y);                                          \
    dst[2] = pkrtz((Qm).y, (Qm).z);                                          \
    dst[3] = pkrtz((Qm).z, (Qm).w);                                          \
    dst[4] = pkrtz((Qm).w, hasR ? (Qr).x : 0.0f);                            \
} while (0)

#define CVTW(W_, R_) do {                                                    \
    CVT1(W_.d, R_.dm, R_.dl, R_.dr);                                         \
    CVT1(W_.m, R_.mm, R_.ml, R_.mr);                                         \
    CVT1(W_.x, R_.xm, R_.xl, R_.xr);                                         \
    CVT1(W_.y, R_.ym, R_.yl, R_.yr);                                         \
    CVT1(W_.z, R_.zm, R_.zl, R_.zr);                                         \
} while (0)

#define ZEROW(W_) do {                                                       \
    _Pragma("unroll") for (int _j = 0; _j < 5; ++_j) {                       \
        W_.d[_j] = h2{0,0}; W_.m[_j] = h2{0,0}; W_.x[_j] = h2{0,0};          \
        W_.y[_j] = h2{0,0}; W_.z[_j] = h2{0,0};                              \
    }                                                                        \
} while (0)

#define TAP(S_, pi, cD, cX, cY, cZ, WSC, A_) do {                            \
    const h2 _wd = wpoly(S_.d[pi] - (cD));                                   \
    const h2 _w0 = wpoly(S_.x[pi] - (cX));                                   \
    const h2 _w1 = wpoly(S_.y[pi] - (cY));                                   \
    const h2 _w2 = wpoly(S_.z[pi] - (cZ));                                   \
    const h2 _wc = _w0 + _w1 + _w2;                                          \
    const h2 _t  = (_wd * _wc) * (H2c(WSC) * S_.m[pi]);                      \
    A_.swd += _wd; A_.swc += _wc; A_.st += _t;                               \
    A_.s0 += _t * S_.x[pi]; A_.s1 += _t * S_.y[pi]; A_.s2 += _t * S_.z[pi];  \
} while (0)

// Self-row pass with center taps folded: packs 1 and 3 vs themselves give
// wd = 1, wc = 3 exactly (all diffs zero).
#define ROWPASS_C(S_, A0_, A1_) do {                                         \
    TAP(S_, 0, S_.d[1], S_.x[1], S_.y[1], S_.z[1], WS1f, A0_);               \
    { const h2 _t = H2c(3.0f * WS0f) * S_.m[1];                              \
      A0_.swd += H2c(1.0f); A0_.swc += H2c(3.0f); A0_.st += _t;              \
      A0_.s0 += _t * S_.x[1]; A0_.s1 += _t * S_.y[1]; A0_.s2 += _t * S_.z[1]; } \
    TAP(S_, 2, S_.d[1], S_.x[1], S_.y[1], S_.z[1], WS1f, A0_);               \
    TAP(S_, 2, S_.d[3], S_.x[3], S_.y[3], S_.z[3], WS1f, A1_);               \
    { const h2 _t = H2c(3.0f * WS0f) * S_.m[3];                              \
      A1_.swd += H2c(1.0f); A1_.swc += H2c(3.0f); A1_.st += _t;              \
      A1_.s0 += _t * S_.x[3]; A1_.s1 += _t * S_.y[3]; A1_.s2 += _t * S_.z[3]; } \
    TAP(S_, 4, S_.d[3], S_.x[3], S_.y[3], S_.z[3], WS1f, A1_);               \
} while (0)

// Cross-row pass: source row S_ vs centers (cd0..cz1), weights WSM/WSS.
#define ROWPASS(S_, cd0,cx0,cy0,cz0, cd1,cx1,cy1,cz1, A0_, A1_, WSM, WSS) do { \
    TAP(S_, 0, cd0, cx0, cy0, cz0, WSS, A0_);                                \
    TAP(S_, 1, cd0, cx0, cy0, cz0, WSM, A0_);                                \
    TAP(S_, 2, cd0, cx0, cy0, cz0, WSS, A0_);                                \
    TAP(S_, 2, cd1, cx1, cy1, cz1, WSS, A1_);                                \
    TAP(S_, 3, cd1, cx1, cy1, cz1, WSM, A1_);                                \
    TAP(S_, 4, cd1, cx1, cy1, cz1, WSS, A1_);                                \
} while (0)

    const bool hasUp = (hp > 0);
    const bool hasDn = (hp < 255);
    const int  rUp = hasUp ? rA - 1 : rA;      // clamped (valid addr)
    const int  rDn = hasDn ? rA + 2 : rA;

    // Phase 1: all 30 A+B loads in flight before any cvt.
    Raw rawA, rawB;
    LOADRAW(rawA, rA);
    LOADRAW(rawB, rA + 1);

    RW A, B;
    CVTW(A, rawA);
    CVTW(B, rawB);

    Acc aa0{}, aa1{}, ab0{}, ab1{};

    // Self-row passes (center-folded).
    ROWPASS_C(A, aa0, aa1);
    ROWPASS_C(B, ab0, ab1);

    // Phase 2: side-row (up) loads fly under the two cross passes.
    Raw rawT;
    LOADRAW(rawT, rUp);

    ROWPASS(B, A.d[1],A.x[1],A.y[1],A.z[1], A.d[3],A.x[3],A.y[3],A.z[3],
            aa0, aa1, WS1f, WS2f);
    ROWPASS(A, B.d[1],B.x[1],B.y[1],B.z[1], B.d[3],B.x[3],B.y[3],B.z[3],
            ab0, ab1, WS1f, WS2f);

    // Save centers; A/B windows die here.
    const h2 cad0 = A.d[1], cad1 = A.d[3];
    const h2 cax0 = A.x[1], cax1 = A.x[3];
    const h2 cay0 = A.y[1], cay1 = A.y[3];
    const h2 caz0 = A.z[1], caz1 = A.z[3];
    const h2 cbd0 = B.d[1], cbd1 = B.d[3];
    const h2 cbx0 = B.x[1], cbx1 = B.x[3];
    const h2 cby0 = B.y[1], cby1 = B.y[3];
    const h2 cbz0 = B.z[1], cbz1 = B.z[3];

    RW T;
    if (hasUp) CVTW(T, rawT); else ZEROW(T);   // exact zero-pad semantics

    // Phase 3: side-row (down) loads fly under the up-row pass.
    Raw rawT2;
    LOADRAW(rawT2, rDn);

    ROWPASS(T, cad0,cax0,cay0,caz0, cad1,cax1,cay1,caz1, aa0, aa1, WS1f, WS2f);

    if (hasDn) CVTW(T, rawT2); else ZEROW(T);
    ROWPASS(T, cbd0,cbx0,cby0,cbz0, cbd1,cbx1,cby1,cbz1, ab0, ab1, WS1f, WS2f);

    // fp32 epilogue: out = S / (St + 9e-7*Swd*Swc)
#define EPI(A_, o0, o1, o2, i0, i1) do {                                     \
    {                                                                        \
        const float g   = (float)A_.st[0]                                    \
                        + 9e-7f * (float)A_.swd[0] * (float)A_.swc[0];       \
        const float inv = __builtin_amdgcn_rcpf(g);                          \
        o0[i0] = (float)A_.s0[0] * inv;                                      \
        o1[i0] = (float)A_.s1[0] * inv;                                      \
        o2[i0] = (float)A_.s2[0] * inv;                                      \
    }                                                                        \
    {                                                                        \
        const float g   = (float)A_.st[1]                                    \
                        + 9e-7f * (float)A_.swd[1] * (float)A_.swc[1];       \
        const float inv = __builtin_amdgcn_rcpf(g);                          \
        o0[i1] = (float)A_.s0[1] * inv;                                      \
        o1[i1] = (float)A_.s1[1] * inv;                                      \
        o2[i1] = (float)A_.s2[1] * inv;                                      \
    }                                                                        \
} while (0)

    float ra0[4], ra1[4], ra2[4], rb0[4], rb1[4], rb2[4];
    EPI(aa0, ra0, ra1, ra2, 0, 1);
    EPI(aa1, ra0, ra1, ra2, 2, 3);
    EPI(ab0, rb0, rb1, rb2, 0, 1);
    EPI(ab1, rb0, rb1, rb2, 2, 3);

    float* po = out + (size_t)n * 3 * HW + rA * WW + c0;
    *reinterpret_cast<float4*>(po)               = make_float4(ra0[0], ra0[1], ra0[2], ra0[3]);
    *reinterpret_cast<float4*>(po + HW)          = make_float4(ra1[0], ra1[1], ra1[2], ra1[3]);
    *reinterpret_cast<float4*>(po + 2 * HW)      = make_float4(ra2[0], ra2[1], ra2[2], ra2[3]);
    *reinterpret_cast<float4*>(po + WW)          = make_float4(rb0[0], rb0[1], rb0[2], rb0[3]);
    *reinterpret_cast<float4*>(po + WW + HW)     = make_float4(rb1[0], rb1[1], rb1[2], rb1[3]);
    *reinterpret_cast<float4*>(po + WW + 2 * HW) = make_float4(rb2[0], rb2[1], rb2[2], rb2[3]);
}

extern "C" void kernel_launch(void* const* d_in, const int* in_sizes, int n_in,
                              void* d_out, int out_size, void* d_ws, size_t ws_size,
                              hipStream_t stream) {
    const float* depth = (const float*)d_in[0];
    const float* color = (const float*)d_in[1];
    const float* mask  = (const float*)d_in[2];
    float* out = (float*)d_out;

    // 8 images * 256 row-pairs * 2 halves = 4096 waves; 4 waves/block
    bilateral_v13<<<1024, 256, 0, stream>>>(depth, color, mask, out);
}